// Round 1
// baseline (1004.852 us; speedup 1.0000x reference)
//
#include <hip/hip_runtime.h>
#include <hip/hip_bf16.h>

typedef __bf16 bf16;
typedef bf16 bf16x8 __attribute__((ext_vector_type(8)));
typedef bf16 bf16x4 __attribute__((ext_vector_type(4)));
typedef float floatx4 __attribute__((ext_vector_type(4)));

#define LDS_STRIDE 136   // 128 + 8 bf16 pad: keeps 16B alignment, breaks pow2 bank stride

// ---------------------------------------------------------------------------
// Repack weights: fp32 [K][N] row-major  ->  bf16 [N][K] (transposed) so that
// MFMA B-fragments (8 contiguous k per lane) are single 16B global loads.
// ---------------------------------------------------------------------------
__global__ void repack_weights(const float* __restrict__ W0,
                               const float* __restrict__ W1,
                               const float* __restrict__ W2,
                               bf16* __restrict__ Wt0,
                               bf16* __restrict__ Wt1,
                               bf16* __restrict__ Wt2) {
    int t = blockIdx.x * blockDim.x + threadIdx.x;
    const int S0 = 384 * 128, S1 = 128 * 128;
    if (t < S0) {
        int k = t >> 7, n = t & 127;
        Wt0[n * 384 + k] = (bf16)W0[t];
    } else if (t < S0 + S1) {
        int i = t - S0;
        int k = i >> 7, n = i & 127;
        Wt1[n * 128 + k] = (bf16)W1[i];
    } else if (t < S0 + 2 * S1) {
        int i = t - S0 - S1;
        int k = i >> 7, n = i & 127;
        Wt2[n * 128 + k] = (bf16)W2[i];
    }
}

// ---------------------------------------------------------------------------
// Fused 3-layer MLP. Block handles 128 rows (edges) x 128 cols.
// 4 waves in a 2x2 grid, each wave owns a 64x64 sub-tile (4x4 MFMA frags).
// Layer 0 (K=384) streams the 3 concat chunks through one LDS tile.
// h round-trips through the same LDS tile between layers (bias+SiLU fused).
// ---------------------------------------------------------------------------
__global__ void edge_mlp(const float* __restrict__ src,
                         const float* __restrict__ dest,
                         const float* __restrict__ edge_attr,
                         const bf16* __restrict__ Wt0,
                         const bf16* __restrict__ Wt1,
                         const bf16* __restrict__ Wt2,
                         const float* __restrict__ b0,
                         const float* __restrict__ b1,
                         const float* __restrict__ b2,
                         float* __restrict__ out,
                         int E) {
    __shared__ bf16 Ax[128 * LDS_STRIDE];   // 34,816 B

    const int tid  = threadIdx.x;
    const int wave = tid >> 6;
    const int lane = tid & 63;
    const int wm   = wave >> 1;       // 0..1 : row half
    const int wn   = wave & 1;        // 0..1 : col half
    const int l15  = lane & 15;
    const int quad = lane >> 4;       // 0..3

    const long row0 = (long)blockIdx.x * 128;

    const floatx4 zero4 = {0.f, 0.f, 0.f, 0.f};
    floatx4 acc[4][4];
#pragma unroll
    for (int i = 0; i < 4; ++i)
#pragma unroll
        for (int j = 0; j < 4; ++j) acc[i][j] = zero4;

    // --- GEMM over the current LDS tile (K=128) against transposed weights ---
    auto gemm_tile = [&](const bf16* __restrict__ Wt, int wstride, int kofs) {
#pragma unroll
        for (int ks = 0; ks < 4; ++ks) {
            const int kk = ks * 32 + quad * 8;      // local k for A (LDS)
            bf16x8 a[4], b[4];
#pragma unroll
            for (int i = 0; i < 4; ++i) {
                int r = wm * 64 + i * 16 + l15;
                a[i] = *(const bf16x8*)&Ax[r * LDS_STRIDE + kk];
            }
#pragma unroll
            for (int j = 0; j < 4; ++j) {
                int n = wn * 64 + j * 16 + l15;
                b[j] = *(const bf16x8*)(Wt + n * wstride + kofs + kk);
            }
#pragma unroll
            for (int i = 0; i < 4; ++i)
#pragma unroll
                for (int j = 0; j < 4; ++j)
                    acc[i][j] = __builtin_amdgcn_mfma_f32_16x16x32_bf16(
                        a[i], b[j], acc[i][j], 0, 0, 0);
        }
    };

    // --- bias + SiLU epilogue: acc (C-layout) -> bf16 LDS (A-layout), reset acc ---
    auto epilogue_silu = [&](const float* __restrict__ bias) {
#pragma unroll
        for (int j = 0; j < 4; ++j) {
            int n = wn * 64 + j * 16 + l15;
            float bv = bias[n];
#pragma unroll
            for (int i = 0; i < 4; ++i) {
                int rb = wm * 64 + i * 16 + quad * 4;
#pragma unroll
                for (int q = 0; q < 4; ++q) {
                    float x = acc[i][j][q] + bv;
                    float s = x / (1.f + __expf(-x));
                    Ax[(rb + q) * LDS_STRIDE + n] = (bf16)s;
                }
                acc[i][j] = zero4;
            }
        }
    };

    // ---------------- Layer 0: K = 384, concat order [edge_attr, src, dest] ----
    const float* chunk_ptr[3] = {edge_attr, src, dest};
    for (int c = 0; c < 3; ++c) {
        const float* __restrict__ xin = chunk_ptr[c];
        // stage 128x128 fp32 -> bf16 into LDS (coalesced float4 reads)
#pragma unroll
        for (int it = 0; it < 16; ++it) {
            int r  = it * 8 + (tid >> 5);
            int c4 = (tid & 31) * 4;
            long gr = row0 + r;
            float4 v;
            if (gr < E) v = *(const float4*)(xin + gr * 128 + c4);
            else        v = make_float4(0.f, 0.f, 0.f, 0.f);
            bf16x4 bv;
            bv[0] = (bf16)v.x; bv[1] = (bf16)v.y;
            bv[2] = (bf16)v.z; bv[3] = (bf16)v.w;
            *(bf16x4*)&Ax[r * LDS_STRIDE + c4] = bv;
        }
        __syncthreads();
        gemm_tile(Wt0, 384, c * 128);
        __syncthreads();
    }
    epilogue_silu(b0);
    __syncthreads();

    // ---------------- Layer 1: K = 128 ----------------
    gemm_tile(Wt1, 128, 0);
    __syncthreads();
    epilogue_silu(b1);
    __syncthreads();

    // ---------------- Layer 2: K = 128, no activation, store fp32 -------------
    gemm_tile(Wt2, 128, 0);
#pragma unroll
    for (int j = 0; j < 4; ++j) {
        int n = wn * 64 + j * 16 + l15;
        float bv = b2[n];
#pragma unroll
        for (int i = 0; i < 4; ++i) {
            int rb = wm * 64 + i * 16 + quad * 4;
#pragma unroll
            for (int q = 0; q < 4; ++q) {
                long gr = row0 + rb + q;
                if (gr < E) out[gr * 128 + n] = acc[i][j][q] + bv;
            }
        }
    }
}

extern "C" void kernel_launch(void* const* d_in, const int* in_sizes, int n_in,
                              void* d_out, int out_size, void* d_ws, size_t ws_size,
                              hipStream_t stream) {
    const float* src       = (const float*)d_in[0];
    const float* dest      = (const float*)d_in[1];
    const float* edge_attr = (const float*)d_in[2];
    const float* W0        = (const float*)d_in[3];
    const float* b0        = (const float*)d_in[4];
    const float* W1        = (const float*)d_in[5];
    const float* b1        = (const float*)d_in[6];
    const float* W2        = (const float*)d_in[7];
    const float* b2        = (const float*)d_in[8];
    float*       out       = (float*)d_out;

    const int E = in_sizes[0] / 128;

    bf16* Wt0 = (bf16*)d_ws;            // [128][384] bf16 = 98,304 B
    bf16* Wt1 = Wt0 + 128 * 384;        // [128][128] bf16 = 32,768 B
    bf16* Wt2 = Wt1 + 128 * 128;        // [128][128] bf16 = 32,768 B

    repack_weights<<<(384 * 128 + 2 * 128 * 128 + 255) / 256, 256, 0, stream>>>(
        W0, W1, W2, Wt0, Wt1, Wt2);

    const int nblk = (E + 127) / 128;
    edge_mlp<<<nblk, 256, 0, stream>>>(src, dest, edge_attr, Wt0, Wt1, Wt2,
                                       b0, b1, b2, out, E);
}